// Round 5
// baseline (151.391 us; speedup 1.0000x reference)
//
#include <hip/hip_runtime.h>

#define D 128

typedef __attribute__((ext_vector_type(8))) short short8;
typedef __attribute__((ext_vector_type(4))) float f32x4;

// ---------- bf16 helpers (manual, RNE) ----------
static __device__ __forceinline__ unsigned short f2bf(float f) {
    unsigned int u = __float_as_uint(f);
    u += 0x7fffu + ((u >> 16) & 1u);
    return (unsigned short)(u >> 16);
}
static __device__ __forceinline__ float bf_lo(unsigned int v) {
    return __uint_as_float(v << 16);
}
static __device__ __forceinline__ float bf_hi(unsigned int v) {
    return __uint_as_float(v & 0xffff0000u);
}

// ---------- MFMA GEMM: hs = (x @ W) * dinv[row], stored bf16 ----------
__global__ __launch_bounds__(256) void gemm_mfma(const float* __restrict__ x,
                                                 const float* __restrict__ W,
                                                 const float* __restrict__ dinv,
                                                 unsigned short* __restrict__ h,
                                                 int N) {
    __shared__ unsigned short Wt[D * D];       // transposed W, bf16, XOR-swizzled (32 KB)
    __shared__ unsigned short ost[4][16 * D];  // per-wave output stage (16 KB)

    int t = threadIdx.x;
    int w = t >> 6, l = t & 63;
    int mrow = l & 15, kgrp = l >> 4;

    // ---- stage Wt[c][k] = bf16(W[k][c]), swizzled: byte ^= (c&7)<<4 ----
    {
        const float4* Wv = (const float4*)W;
        for (int i = 0; i < 16; ++i) {
            int idx = i * 256 + t;       // 4096 float4 total
            int k = idx >> 5;            // W row
            int c0 = (idx & 31) * 4;     // W col
            float4 v = Wv[idx];
            float vv[4] = {v.x, v.y, v.z, v.w};
#pragma unroll
            for (int j = 0; j < 4; ++j) {
                int c = c0 + j;
                unsigned int B = (unsigned int)c * 256 + (unsigned int)k * 2;
                unsigned int sB = B ^ (((unsigned int)c & 7u) << 4);
                *(unsigned short*)((char*)Wt + sB) = f2bf(vv[j]);
            }
        }
    }
    __syncthreads();

    for (int rt = 0; rt < 2; ++rt) {
        int row0 = blockIdx.x * 128 + w * 32 + rt * 16;  // N % 16 == 0
        bool act = row0 < N;

        if (act) {
            short8 a[4];
#pragma unroll
            for (int kk = 0; kk < 4; ++kk) {
                const float* p = &x[(size_t)(row0 + mrow) * D + kk * 32 + kgrp * 8];
                float4 q0 = *(const float4*)p;
                float4 q1 = *(const float4*)(p + 4);
                short8 af;
                af[0] = (short)f2bf(q0.x); af[1] = (short)f2bf(q0.y);
                af[2] = (short)f2bf(q0.z); af[3] = (short)f2bf(q0.w);
                af[4] = (short)f2bf(q1.x); af[5] = (short)f2bf(q1.y);
                af[6] = (short)f2bf(q1.z); af[7] = (short)f2bf(q1.w);
                a[kk] = af;
            }
            f32x4 acc[8];
#pragma unroll
            for (int nt = 0; nt < 8; ++nt) {
                acc[nt] = (f32x4){0.f, 0.f, 0.f, 0.f};
#pragma unroll
                for (int kk = 0; kk < 4; ++kk) {
                    unsigned int c = nt * 16 + mrow;
                    unsigned int B = c * 256 + (unsigned int)(kk * 32 + kgrp * 8) * 2;
                    unsigned int sB = B ^ ((c & 7u) << 4);
                    short8 bf = *(const short8*)((char*)Wt + sB);
                    acc[nt] = __builtin_amdgcn_mfma_f32_16x16x32_bf16(a[kk], bf, acc[nt], 0, 0, 0);
                }
            }
            float dv[4];
#pragma unroll
            for (int j = 0; j < 4; ++j) dv[j] = dinv[row0 + kgrp * 4 + j];
#pragma unroll
            for (int nt = 0; nt < 8; ++nt)
#pragma unroll
                for (int j = 0; j < 4; ++j) {
                    int rr = kgrp * 4 + j;
                    ost[w][rr * D + nt * 16 + mrow] = f2bf(acc[nt][j] * dv[j]);
                }
        }
        __syncthreads();
        if (act) {
            const uint4* os4 = (const uint4*)ost[w];
            uint4* H4 = (uint4*)h;
#pragma unroll
            for (int i2 = 0; i2 < 4; ++i2) {
                int e = i2 * 64 + l;
                H4[(size_t)row0 * 16 + e] = os4[e];
            }
        }
        __syncthreads();
    }
}

// ---------- degree count over dst (vectorized) ----------
__global__ void count_k(const int* __restrict__ dst, int* __restrict__ cnt, int E) {
    int e = (blockIdx.x * blockDim.x + threadIdx.x) * 4;
    if (e + 3 < E) {
        int4 d = *(const int4*)&dst[e];
        atomicAdd(&cnt[d.x], 1);
        atomicAdd(&cnt[d.y], 1);
        atomicAdd(&cnt[d.z], 1);
        atomicAdd(&cnt[d.w], 1);
    } else {
        for (int q = e; q < E; ++q) atomicAdd(&cnt[dst[q]], 1);
    }
}

// ---------- scan phase A + fused dinv ----------
__global__ __launch_bounds__(256) void scan_a(const int* __restrict__ cnt,
                                              int* __restrict__ rowstart,
                                              int* __restrict__ bsum,
                                              float* __restrict__ dinv, int N) {
    __shared__ int sh[256];
    int t = threadIdx.x;
    int base = blockIdx.x * 1024 + t * 4;
    int v[4];
#pragma unroll
    for (int j = 0; j < 4; ++j) v[j] = (base + j < N) ? cnt[base + j] : 0;
#pragma unroll
    for (int j = 0; j < 4; ++j)
        if (base + j < N) dinv[base + j] = rsqrtf((float)v[j] + 1.0f);
    int ts = v[0] + v[1] + v[2] + v[3];
    sh[t] = ts;
    __syncthreads();
    for (int off = 1; off < 256; off <<= 1) {
        int u = (t >= off) ? sh[t - off] : 0;
        __syncthreads();
        sh[t] += u;
        __syncthreads();
    }
    int run = sh[t] - ts;
#pragma unroll
    for (int j = 0; j < 4; ++j) {
        if (base + j < N) rowstart[base + j] = run;
        run += v[j];
    }
    if (t == 255) bsum[blockIdx.x] = sh[255];
}

__global__ void scan_b(const int* __restrict__ bsum, int* __restrict__ boff,
                       int nb, int* __restrict__ rowstart, int N) {
    __shared__ int sh[128];
    int t = threadIdx.x;
    int v = (t < nb) ? bsum[t] : 0;
    sh[t] = v;
    __syncthreads();
    for (int off = 1; off < 128; off <<= 1) {
        int u = (t >= off) ? sh[t - off] : 0;
        __syncthreads();
        sh[t] += u;
        __syncthreads();
    }
    if (t < nb) boff[t] = sh[t] - v;
    if (t == 127) rowstart[N] = sh[127];
}

// finalize rowstart and init cursor = rowstart (absolute fill positions)
__global__ void scan_c(int* __restrict__ rowstart, const int* __restrict__ boff,
                       int* __restrict__ cursor, int N) {
    int i = blockIdx.x * blockDim.x + threadIdx.x;
    if (i < N) {
        int r = rowstart[i] + boff[i >> 10];
        rowstart[i] = r;
        cursor[i] = r;
    }
}

// ---------- fill CSR edge lists (src per dst), absolute cursor ----------
__global__ void fill_k(const int* __restrict__ ei, int* __restrict__ cursor,
                       int* __restrict__ eidx, int E) {
    int e = blockIdx.x * blockDim.x + threadIdx.x;
    if (e < E) {
        int s = ei[e];
        int d = ei[E + e];
        int p = atomicAdd(&cursor[d], 1);
        eidx[p] = s;
    }
}

// ---------- pull-mode aggregate + bias + relu + residual (fused) ----------
// hs rows pre-scaled by dinv[src]; agg = di * (hs[i] + sum hs[src])
// Two 32-lane halves handle edges k+half; ALL loop conditions are
// wave-uniform (deg is per-wave uniform) so every __shfl executes with the
// full 64-lane exec mask — shfl from an exec-masked-off lane is UNDEFINED
// on CDNA and was the round-3/4 correctness bug.
__global__ __launch_bounds__(256) void agg_k(const unsigned int* __restrict__ h2,
                                             const float* __restrict__ x,
                                             const float* __restrict__ b,
                                             const float* __restrict__ dinv,
                                             const int* __restrict__ rowstart,
                                             const int* __restrict__ eidx,
                                             float* __restrict__ out, int N) {
    int w = threadIdx.x >> 6;
    int lane = threadIdx.x & 63;
    int half = lane >> 5;
    int sl = lane & 31;
    int i = blockIdx.x * 4 + w;
    if (i >= N) return;

    int rs = rowstart[i];
    int re = rowstart[i + 1];
    int deg = re - rs;   // wave-uniform
    float di = dinv[i];

    const uint2* H = (const uint2*)h2;

    // preload up to 64 edge indices in one coalesced round
    int idxv = 0;
    if (lane < deg) idxv = eidx[rs + lane];

    float a0 = 0.f, a1 = 0.f, a2 = 0.f, a3 = 0.f;
    if (half == 0) {  // self-loop row: half-wave covers the full 256B row
        uint2 sv = H[(size_t)i * 32 + sl];
        a0 = bf_lo(sv.x); a1 = bf_hi(sv.x);
        a2 = bf_lo(sv.y); a3 = bf_hi(sv.y);
    }

    int dk = deg < 64 ? deg : 64;  // wave-uniform
    int k = 0;
    for (; k + 3 < dk; k += 4) {   // uniform cond; 4 edges/iter, 4 gathers in flight
        int sA = __shfl(idxv, k + half, 64);
        int sB = __shfl(idxv, k + 2 + half, 64);
        uint2 vA = H[(size_t)sA * 32 + sl];
        uint2 vB = H[(size_t)sB * 32 + sl];
        a0 += bf_lo(vA.x) + bf_lo(vB.x);
        a1 += bf_hi(vA.x) + bf_hi(vB.x);
        a2 += bf_lo(vA.y) + bf_lo(vB.y);
        a3 += bf_hi(vA.y) + bf_hi(vB.y);
    }
    if (k + 1 < dk) {              // uniform cond; 2 edges
        int sA = __shfl(idxv, k + half, 64);
        uint2 vA = H[(size_t)sA * 32 + sl];
        a0 += bf_lo(vA.x); a1 += bf_hi(vA.x);
        a2 += bf_lo(vA.y); a3 += bf_hi(vA.y);
        k += 2;
    }
    if (k < dk) {                  // uniform cond; 1 edge, uniform source lane
        int sA = __shfl(idxv, k, 64);
        if (half == 0) {           // only the load is predicated, not the shfl
            uint2 vA = H[(size_t)sA * 32 + sl];
            a0 += bf_lo(vA.x); a1 += bf_hi(vA.x);
            a2 += bf_lo(vA.y); a3 += bf_hi(vA.y);
        }
    }
    for (int p = 64 + half; p < deg; p += 2) {  // rare: deg > 64 (no shfl here)
        int sA = eidx[rs + p];
        uint2 vA = H[(size_t)sA * 32 + sl];
        a0 += bf_lo(vA.x); a1 += bf_hi(vA.x);
        a2 += bf_lo(vA.y); a3 += bf_hi(vA.y);
    }

    // combine the two halves (wave fully reconverged here)
    a0 += __shfl_xor(a0, 32, 64);
    a1 += __shfl_xor(a1, 32, 64);
    a2 += __shfl_xor(a2, 32, 64);
    a3 += __shfl_xor(a3, 32, 64);

    if (half == 0) {
        float4 bb = *(const float4*)&b[sl * 4];
        float4 xx = *(const float4*)&x[(size_t)i * D + sl * 4];
        float4 o;
        o.x = xx.x + fmaxf(a0 * di + bb.x, 0.f);
        o.y = xx.y + fmaxf(a1 * di + bb.y, 0.f);
        o.z = xx.z + fmaxf(a2 * di + bb.z, 0.f);
        o.w = xx.w + fmaxf(a3 * di + bb.w, 0.f);
        *(float4*)&out[(size_t)i * D + sl * 4] = o;
    }
}

extern "C" void kernel_launch(void* const* d_in, const int* in_sizes, int n_in,
                              void* d_out, int out_size, void* d_ws, size_t ws_size,
                              hipStream_t stream) {
    const float* x = (const float*)d_in[0];
    const int* ei = (const int*)d_in[1];
    const float* W = (const float*)d_in[2];
    const float* b = (const float*)d_in[3];
    float* out = (float*)d_out;

    int N = in_sizes[0] / D;
    int E = in_sizes[1] / 2;

    char* ws = (char*)d_ws;
    float* dinv      = (float*)(ws + 0);
    int* cnt         = (int*)(ws + (512 << 10));
    int* rowstart    = (int*)(ws + (1024 << 10));
    int* cursor      = (int*)(ws + (1536 << 10));
    int* bsum        = (int*)(ws + (2048 << 10));
    int* boff        = (int*)(ws + (2048 << 10) + 4096);
    int* eidx        = (int*)(ws + (2056 << 10));             // E*4 = 2.44 MB
    unsigned short* h = (unsigned short*)(ws + (4608 << 10)); // N*128*2 = 24.4 MB
    unsigned int* h2 = (unsigned int*)h;

    hipMemsetAsync(cnt, 0, (size_t)N * 4, stream);

    count_k<<<((E + 3) / 4 + 255) / 256, 256, 0, stream>>>(ei + E, cnt, E);
    int nb = (N + 1023) / 1024;
    scan_a<<<nb, 256, 0, stream>>>(cnt, rowstart, bsum, dinv, N);
    scan_b<<<1, 128, 0, stream>>>(bsum, boff, nb, rowstart, N);
    scan_c<<<(N + 255) / 256, 256, 0, stream>>>(rowstart, boff, cursor, N);
    gemm_mfma<<<(N + 127) / 128, 256, 0, stream>>>(x, W, dinv, h, N);
    fill_k<<<(E + 255) / 256, 256, 0, stream>>>(ei, cursor, eidx, E);
    agg_k<<<(N + 3) / 4, 256, 0, stream>>>(h2, x, b, dinv, rowstart, eidx, out, N);
}